// Round 3
// baseline (125.133 us; speedup 1.0000x reference)
//
#include <hip/hip_runtime.h>
#include <hip/hip_bf16.h>
#include <stdint.h>

typedef short bf16x8 __attribute__((ext_vector_type(8)));
typedef float f32x16 __attribute__((ext_vector_type(16)));

#define NROWS 8192
#define CDIM  128
#define TEMP  0.07f
// log2(e)/0.07
#define C1F   20.6099291555566248f
#define MAGIC 0x13579BDF

// ws layout (bytes). Xb at 0 (2 MB). All partial arrays are single-writer at
// 64B-line granularity (no false sharing across XCD L2 writebacks).
#define OFF_SPART 2097152              // float[16][8192]  = 512 KB
#define OFF_GPART 2621440              // float[128][4][16] = 32 KB
#define OFF_HPART 2654208              // int[16][16] (64B/entry pad) = 1 KB
#define OFF_SLP   2655232              // float[32][16] (64B/entry pad) = 2 KB
#define OFF_PFLAG 2657280              // int[257] pack flags + ticket-init flag
#define OFF_GFLAG 2658368              // int[128] gsum flags
#define OFF_TKT   2658880              // int mainTicket
#define OFF_TKT2  2658884              // int lossTicket

__device__ __forceinline__ float bf2f(unsigned short u) {
  union { unsigned int i; float f; } x; x.i = ((unsigned int)u) << 16; return x.f;
}
__device__ __forceinline__ unsigned short f2bf(float f) {
  union { float f; unsigned int i; } x; x.f = f;
  unsigned int r = x.i + 0x7fffu + ((x.i >> 16) & 1u);  // RNE
  return (unsigned short)(r >> 16);
}
__device__ __forceinline__ float fexp2(float x) {
#if __has_builtin(__builtin_amdgcn_exp2f)
  return __builtin_amdgcn_exp2f(x);
#else
  return exp2f(x);
#endif
}
__device__ __forceinline__ int aload(int* p) {
  return __hip_atomic_load(p, __ATOMIC_RELAXED, __HIP_MEMORY_SCOPE_AGENT);
}
__device__ __forceinline__ void astore(int* p, int v) {
  __hip_atomic_store(p, v, __ATOMIC_RELAXED, __HIP_MEMORY_SCOPE_AGENT);
}

// One kernel, grid=1024 (exactly 4 blocks/CU co-resident; workers are blocks
// 0..255 and dependency-free, so progress is guaranteed regardless of
// dispatch order as long as residency holds -- and even without full
// residency, ascending-ID dispatch retires workers first).
__global__ __launch_bounds__(256, 4) void k_fused(const float* __restrict__ F,
                                                  const int* __restrict__ labels,
                                                  char* __restrict__ ws,
                                                  float* __restrict__ out) {
  unsigned short* Xb    = (unsigned short*)ws;
  float*          Spart = (float*)(ws + OFF_SPART);
  float*          Gpart = (float*)(ws + OFF_GPART);
  int*            Hpart = (int*)(ws + OFF_HPART);
  float*          SLP   = (float*)(ws + OFF_SLP);
  int*            pflag = (int*)(ws + OFF_PFLAG);
  int*            gflag = (int*)(ws + OFF_GFLAG);
  int*            tkt   = (int*)(ws + OFF_TKT);
  int*            tkt2  = (int*)(ws + OFF_TKT2);

  __shared__ int4 smem4[2112];  // 33792 B, unioned across phases
  char* smem = (char*)smem4;

  const int tid  = threadIdx.x;
  const int bid  = blockIdx.x;
  const int lane = tid & 63;
  const int wave = tid >> 6;

  // ======================= worker phase (blocks 0..255) ====================
  if (bid < 256) {
    if (bid == 0 && tid == 0) {
      astore(tkt, 0);
      astore(tkt2, 0);
      __hip_atomic_store(&pflag[256], MAGIC, __ATOMIC_RELEASE,
                         __HIP_MEMORY_SCOPE_AGENT);
    }
    // ---- pack tile bid: rows bid*32..+31 of X (bf16), LDS transpose ----
    {
      float* lds = (float*)smem;
      const int g = bid >> 5, hw0 = (bid & 31) << 5;
#pragma unroll
      for (int p = 0; p < 16; ++p) {
        int c  = p * 8 + (tid >> 5);
        int hw = hw0 + (tid & 31);
        lds[c * 33 + (tid & 31)] = F[(g * 128 + c) * 1024 + hw];
      }
      __syncthreads();
#pragma unroll
      for (int p = 0; p < 16; ++p) {
        int hwl = p * 2 + (tid >> 7);
        int c   = tid & 127;
        int row = g * 1024 + hw0 + hwl;
        Xb[row * 128 + c] = f2bf(lds[c * 33 + hwl]);
      }
      __syncthreads();  // drains vmcnt: all block stores are in L2
      if (tid == 0) {
        __builtin_amdgcn_fence(__ATOMIC_RELEASE, "agent");  // wbl2 -> LLC
        astore(&pflag[bid], MAGIC);
      }
    }
    // ---- gsum unit bid (blocks 0..127): G/hist partials from F ----
    if (bid < 128) {
      const int rchunk = bid >> 3;
      const int cbase  = (bid & 7) * 16;
      const int cl     = tid & 15;
      const int rg     = tid >> 4;  // 0..15
      float a0 = 0.f, a1 = 0.f, a2 = 0.f, a3 = 0.f;
      int   h0 = 0, h1 = 0, h2 = 0, h3 = 0;
      const bool doHist = ((bid & 7) == 0) && (cl == 0);
      for (int j = rg; j < 512; j += 16) {
        int   n   = rchunk * 512 + j;
        int   lab = labels[n];
        float v   = bf2f(f2bf(F[((n >> 10) * 128 + cbase + cl) * 1024 + (n & 1023)]));
        a0 += (lab == 0) ? v : 0.f;
        a1 += (lab == 1) ? v : 0.f;
        a2 += (lab == 2) ? v : 0.f;
        a3 += (lab == 3) ? v : 0.f;
        if (doHist) { h0 += (lab == 0); h1 += (lab == 1); h2 += (lab == 2); h3 += (lab == 3); }
      }
      a0 += __shfl_xor(a0, 16, 64); a0 += __shfl_xor(a0, 32, 64);
      a1 += __shfl_xor(a1, 16, 64); a1 += __shfl_xor(a1, 32, 64);
      a2 += __shfl_xor(a2, 16, 64); a2 += __shfl_xor(a2, 32, 64);
      a3 += __shfl_xor(a3, 16, 64); a3 += __shfl_xor(a3, 32, 64);
      float* lds_g = (float*)smem;        // [4 waves][4 lab][16 ch]
      int*   lds_h = (int*)(smem + 1024); // [16 rg][4 lab]
      if (lane < 16) {
        lds_g[wave * 64 + 0 * 16 + lane] = a0;
        lds_g[wave * 64 + 1 * 16 + lane] = a1;
        lds_g[wave * 64 + 2 * 16 + lane] = a2;
        lds_g[wave * 64 + 3 * 16 + lane] = a3;
      }
      if (doHist) {
        lds_h[rg * 4 + 0] = h0; lds_h[rg * 4 + 1] = h1;
        lds_h[rg * 4 + 2] = h2; lds_h[rg * 4 + 3] = h3;
      }
      __syncthreads();
      if (tid < 64) {
        int l = tid >> 4, c = tid & 15;
        float s = 0.f;
#pragma unroll
        for (int w = 0; w < 4; ++w) s += lds_g[w * 64 + l * 16 + c];
        Gpart[bid * 64 + l * 16 + c] = s;
      }
      if (((bid & 7) == 0) && tid < 4) {
        int hs = 0;
#pragma unroll
        for (int r = 0; r < 16; ++r) hs += lds_h[r * 4 + tid];
        Hpart[(bid >> 3) * 16 + tid] = hs;
      }
      __syncthreads();  // drain partial stores
      if (tid == 0) {
        __builtin_amdgcn_fence(__ATOMIC_RELEASE, "agent");
        astore(&gflag[bid], MAGIC);
      }
    }
  }

  // ======================= main phase (all 1024 blocks) ====================
  const int rb   = bid >> 4;
  const int sp   = bid & 15;
  const int r0   = rb * 128 + wave * 32;
  const int col0 = sp * 512;
  const int m    = lane & 31;
  const int half = lane >> 5;

  // wait: 4 row pack flags + 16 col pack flags + ticket-init flag
  {
    int fidx = 256;
    if (tid < 4) fidx = rb * 4 + tid;
    else if (tid < 20) fidx = sp * 16 + (tid - 4);
    int ok;
    do {
      ok = 1;
      if (tid < 21) ok = (aload(&pflag[fidx]) == MAGIC);
      if (!ok) __builtin_amdgcn_s_sleep(2);
    } while (!__syncthreads_and(ok));
    __builtin_amdgcn_fence(__ATOMIC_ACQUIRE, "workgroup");
  }

  bf16x8 afrag[8];
#pragma unroll
  for (int s = 0; s < 8; ++s)
    afrag[s] = *(const bf16x8*)(Xb + (r0 + m) * CDIM + (half + 2 * s) * 8);

  float accS[16];
#pragma unroll
  for (int r = 0; r < 16; ++r) accS[r] = 0.f;

  // B staging: 64 cols per barrier-iteration, double-buffered.
  // LDS int4 (kchunk c, col n) at (buf*2+u)*528 + c*33 + n.
#define LB(buf, u, idx) smem4[((buf) * 2 + (u)) * 528 + (idx)]
  const int n_l = tid >> 3;
  const int bq  = tid & 7;
  const unsigned short* src = Xb + (col0 + n_l) * CDIM + bq * 16;
  int4 v0 = *(const int4*)src;
  int4 v1 = *(const int4*)(src + 8);
  int4 v2 = *(const int4*)(src + 32 * CDIM);
  int4 v3 = *(const int4*)(src + 32 * CDIM + 8);
  LB(0, 0, (2 * bq) * 33 + n_l)     = v0;
  LB(0, 0, (2 * bq + 1) * 33 + n_l) = v1;
  LB(0, 1, (2 * bq) * 33 + n_l)     = v2;
  LB(0, 1, (2 * bq + 1) * 33 + n_l) = v3;
  src += 64 * CDIM;
  v0 = *(const int4*)src;
  v1 = *(const int4*)(src + 8);
  v2 = *(const int4*)(src + 32 * CDIM);
  v3 = *(const int4*)(src + 32 * CDIM + 8);

  for (int t = 0; t < 8; ++t) {
    __syncthreads();
    if (t < 7) {
      const int nb = (t + 1) & 1;
      LB(nb, 0, (2 * bq) * 33 + n_l)     = v0;
      LB(nb, 0, (2 * bq + 1) * 33 + n_l) = v1;
      LB(nb, 1, (2 * bq) * 33 + n_l)     = v2;
      LB(nb, 1, (2 * bq + 1) * 33 + n_l) = v3;
    }
    if (t < 6) {
      src += 64 * CDIM;
      v0 = *(const int4*)src;
      v1 = *(const int4*)(src + 8);
      v2 = *(const int4*)(src + 32 * CDIM);
      v3 = *(const int4*)(src + 32 * CDIM + 8);
    }
    const int cur = t & 1;
#pragma unroll
    for (int u = 0; u < 2; ++u) {
      f32x16 acc;
#pragma unroll
      for (int r = 0; r < 16; ++r) acc[r] = 0.f;
#pragma unroll
      for (int s = 0; s < 8; ++s) {
        bf16x8 bfrag = *(const bf16x8*)&LB(cur, u, (half + 2 * s) * 33 + m);
        acc = __builtin_amdgcn_mfma_f32_32x32x16_bf16(afrag[s], bfrag, acc, 0, 0, 0);
      }
      const int colbase = col0 + t * 64 + u * 32;
      if (r0 == colbase) {  // only tile that can contain the diagonal
        const int colg = colbase + m;
#pragma unroll
        for (int r = 0; r < 16; ++r) {
          int   row = r0 + (r & 3) + 8 * (r >> 2) + 4 * half;
          float arg = (row == colg) ? -1e30f : acc[r] * C1F;
          accS[r] += fexp2(arg);
        }
      } else {
#pragma unroll
        for (int r = 0; r < 16; ++r) accS[r] += fexp2(acc[r] * C1F);
      }
    }
  }

  // column-reduce within wave halves; single-writer partial store (no atomics)
#pragma unroll
  for (int r = 0; r < 16; ++r) {
    float v = accS[r];
    v += __shfl_xor(v, 1, 64);
    v += __shfl_xor(v, 2, 64);
    v += __shfl_xor(v, 4, 64);
    v += __shfl_xor(v, 8, 64);
    v += __shfl_xor(v, 16, 64);
    accS[r] = v;
  }
  if (m == 0) {
#pragma unroll
    for (int r = 0; r < 16; ++r) {
      int row = r0 + (r & 3) + 8 * (r >> 2) + 4 * half;
      Spart[sp * 8192 + row] = accS[r];
    }
  }

  __syncthreads();  // drain Spart stores into L2
  if (tid == 0) {
    __builtin_amdgcn_fence(__ATOMIC_RELEASE, "agent");  // flush to LLC
    int tt = __hip_atomic_fetch_add(tkt, 1, __ATOMIC_RELAXED,
                                    __HIP_MEMORY_SCOPE_AGENT);
    ((int*)smem)[0] = tt;
  }
  __syncthreads();
  const int t = ((int*)smem)[0];
  if (t < 1024 - 32) return;

  // ======================= loss phase (last 32 ticket-holders) =============
  const int chunk = t - (1024 - 32);
  {
    int ok;
    do {
      ok = 1;
      if (tid < 128)      ok = (aload(&gflag[tid]) == MAGIC);
      else if (tid < 136) ok = (aload(&pflag[chunk * 8 + tid - 128]) == MAGIC);
      else if (tid == 136) ok = (aload(tkt) == 1024);
      if (!ok) __builtin_amdgcn_s_sleep(2);
    } while (!__syncthreads_and(ok));
    __builtin_amdgcn_fence(__ATOMIC_ACQUIRE, "workgroup");
  }
  float* G_lds = (float*)smem;          // [4][128]
  int*   h_lds = (int*)(smem + 2048);   // [4]
  float* red   = (float*)(smem + 2064); // [4]
  int*   comm2 = (int*)(smem + 2080);
#pragma unroll
  for (int e = tid; e < 512; e += 256) {
    int l = e >> 7, c = e & 127;
    float s = 0.f;
#pragma unroll
    for (int r = 0; r < 16; ++r)
      s += Gpart[(r * 8 + (c >> 4)) * 64 + l * 16 + (c & 15)];
    G_lds[e] = s;
  }
  if (tid < 4) {
    int hs = 0;
#pragma unroll
    for (int r = 0; r < 16; ++r) hs += Hpart[r * 16 + tid];
    h_lds[tid] = hs;
  }
  __syncthreads();
  const int i   = chunk * 256 + tid;
  const int lab = labels[i];
  float Si = 0.f;
#pragma unroll
  for (int sp2 = 0; sp2 < 16; ++sp2) Si += Spart[sp2 * 8192 + i];
  const float* gl = G_lds + lab * 128;
  const unsigned short* x = Xb + i * CDIM;
  float dot = 0.f, nrm = 0.f;
#pragma unroll
  for (int cc = 0; cc < 16; ++cc) {
    int4 q = *(const int4*)(x + cc * 8);
    const unsigned int* qs = (const unsigned int*)&q;
#pragma unroll
    for (int j = 0; j < 4; ++j) {
      unsigned int u = qs[j];
      float lo = __uint_as_float(u << 16);
      float hi = __uint_as_float(u & 0xffff0000u);
      int   ci = cc * 8 + j * 2;
      dot += lo * gl[ci] + hi * gl[ci + 1];
      nrm += lo * lo + hi * hi;
    }
  }
  float cnt  = (float)(h_lds[lab] - 1);
  float loss = logf(Si) - (dot - nrm) / (TEMP * cnt);
  float contrib = (lab != 0) ? loss : 0.f;
  for (int mm = 1; mm < 64; mm <<= 1) contrib += __shfl_xor(contrib, mm, 64);
  if (lane == 0) red[wave] = contrib;
  __syncthreads();
  if (tid == 0) {
    float bsum = red[0] + red[1] + red[2] + red[3];
    __hip_atomic_store(&SLP[chunk * 16], bsum, __ATOMIC_RELAXED,
                       __HIP_MEMORY_SCOPE_AGENT);
    int t2 = __hip_atomic_fetch_add(tkt2, 1, __ATOMIC_ACQ_REL,
                                    __HIP_MEMORY_SCOPE_AGENT);
    comm2[0] = (t2 == 31) ? 1 : 0;
  }
  __syncthreads();
  if (comm2[0]) {
    float v = 0.f;
    if (tid < 32)
      v = __hip_atomic_load(&SLP[tid * 16], __ATOMIC_RELAXED,
                            __HIP_MEMORY_SCOPE_AGENT);
    if (tid < 64) {
      for (int mm = 1; mm < 32; mm <<= 1) v += __shfl_xor(v, mm, 64);
    }
    if (tid == 0) out[0] = v / (float)(NROWS - h_lds[0]);
  }
}

// ---------------------------------------------------------------------------
extern "C" void kernel_launch(void* const* d_in, const int* in_sizes, int n_in,
                              void* d_out, int out_size, void* d_ws, size_t ws_size,
                              hipStream_t stream) {
  const float* F      = (const float*)d_in[0];
  const int*   labels = (const int*)d_in[1];
  hipLaunchKernelGGL(k_fused, dim3(1024), dim3(256), 0, stream,
                     F, labels, (char*)d_ws, (float*)d_out);
}

// Round 4
// 113.389 us; speedup vs baseline: 1.1036x; 1.1036x over previous
//
#include <hip/hip_runtime.h>
#include <hip/hip_bf16.h>
#include <stdint.h>

typedef short bf16x8 __attribute__((ext_vector_type(8)));
typedef float f32x16 __attribute__((ext_vector_type(16)));

#define NROWS 8192
#define CDIM  128
#define TEMP  0.07f
// log2(e)/0.07
#define C1F   20.6099291555566248f

// ws layout (bytes from ws base). Xb: [0, 2MB)
#define OFF_S     2097152   // float[8192] = 32768 B   (zeroed by k_pack)
#define OFF_SUM   2129920   // float sumLoss           (zeroed by k_pack)
#define OFF_TKT   2129924   // int ticket              (zeroed by k_pack)
#define OFF_G     2129984   // float[4][128] = 2048 B  (single-writer, k_main tail)
#define OFF_HIST  2132032   // int[4]
#define OFF_GPART 2132096   // float[256][4][128] = 524288 B (k_pack, plain stores)
#define OFF_HPART 2656384   // int[256][4] = 4096 B
#define ZWORDS    8194      // S + sumLoss + ticket contiguous zero region

__device__ __forceinline__ float bf2f(unsigned short u) {
  union { unsigned int i; float f; } x; x.i = ((unsigned int)u) << 16; return x.f;
}
__device__ __forceinline__ unsigned short f2bf(float f) {
  union { float f; unsigned int i; } x; x.f = f;
  unsigned int r = x.i + 0x7fffu + ((x.i >> 16) & 1u);  // RNE
  return (unsigned short)(r >> 16);
}
__device__ __forceinline__ float fexp2(float x) {
#if __has_builtin(__builtin_amdgcn_exp2f)
  return __builtin_amdgcn_exp2f(x);
#else
  return exp2f(x);
#endif
}

// ---------------------------------------------------------------------------
// K1: pack F (fp32 [8][128][1024]) -> Xb bf16 [8192][128]; zero stats region;
// emit per-block label-group sums Gpart[b][4][128] + hist partials Hpart[b][4]
// from the already-LDS-resident tile (32 rows each).
// ---------------------------------------------------------------------------
__global__ __launch_bounds__(256) void k_pack(const float* __restrict__ F,
                                              const int* __restrict__ labels,
                                              char* __restrict__ ws) {
  unsigned short* Xb    = (unsigned short*)ws;
  float*          zbase = (float*)(ws + OFF_S);
  float*          Gpart = (float*)(ws + OFF_GPART);
  int*            Hpart = (int*)(ws + OFF_HPART);

  __shared__ float lds[128 * 33];
  __shared__ float gp[2][4][128];
  __shared__ int   lab_lds[32];

  const int tid = threadIdx.x;
  const int bid = blockIdx.x;

  {  // replaces the hipMemsetAsync node
    int idx = bid * 256 + tid;
    if (idx < ZWORDS) zbase[idx] = 0.0f;
  }

  const int g   = bid >> 5;
  const int hw0 = (bid & 31) << 5;
  const int n0  = g * 1024 + hw0;  // first row of this 32-row tile
  if (tid < 32) lab_lds[tid] = labels[n0 + tid];

#pragma unroll
  for (int p = 0; p < 16; ++p) {
    int c  = p * 8 + (tid >> 5);
    int hw = hw0 + (tid & 31);
    lds[c * 33 + (tid & 31)] = F[(g * 128 + c) * 1024 + hw];
  }
  __syncthreads();

  const int c = tid & 127;
  const int h = tid >> 7;  // wave-uniform
  float a0 = 0.f, a1 = 0.f, a2 = 0.f, a3 = 0.f;
#pragma unroll
  for (int p = 0; p < 16; ++p) {
    int hwl = p * 2 + h;
    float vf = lds[c * 33 + hwl];
    unsigned short vb = f2bf(vf);
    Xb[(n0 + hwl) * 128 + c] = vb;
    float v  = bf2f(vb);
    int  lab = lab_lds[hwl];  // wave-uniform broadcast
    a0 += (lab == 0) ? v : 0.f;
    a1 += (lab == 1) ? v : 0.f;
    a2 += (lab == 2) ? v : 0.f;
    a3 += (lab == 3) ? v : 0.f;
  }
  gp[h][0][c] = a0; gp[h][1][c] = a1; gp[h][2][c] = a2; gp[h][3][c] = a3;
  __syncthreads();
  if (tid < 128) {
#pragma unroll
    for (int l = 0; l < 4; ++l)
      Gpart[bid * 512 + l * 128 + tid] = gp[0][l][tid] + gp[1][l][tid];
  }
  if (tid < 4) {
    int hh = 0;
#pragma unroll
    for (int r = 0; r < 32; ++r) hh += (lab_lds[r] == tid);
    Hpart[bid * 4 + tid] = hh;
  }
}

// ---------------------------------------------------------------------------
// K2: streaming X @ X^T with fused exp-sum. NO LDS, no barriers.
// Gram symmetry: the B-fragment lane map of mfma_32x32x16_bf16 equals the
// A-fragment map, so B frags load directly from Xb (L2-resident) with one
// global_load_dwordx4 per lane. Blocks: 32 rowBlocks(256 rows) x 16 colSplits
// (512 cols) = 512 blocks = 2/CU. Wave owns 64 rows (2 rowsets of 32), loops
// 16 col-groups of 32 with register double-buffered B frags.
// Tail blocks 512..515 reduce Gpart->G and Hpart->hist.
// ---------------------------------------------------------------------------
__global__ __launch_bounds__(256, 2) void k_main(const unsigned short* __restrict__ Xb,
                                                 char* __restrict__ ws) {
  float* S     = (float*)(ws + OFF_S);
  float* Gpart = (float*)(ws + OFF_GPART);
  int*   Hpart = (int*)(ws + OFF_HPART);
  float* G     = (float*)(ws + OFF_G);
  int*   hist  = (int*)(ws + OFF_HIST);

  const int bid = blockIdx.x;
  const int tid = threadIdx.x;

  if (bid >= 512) {  // ---- Gpart/Hpart reduction tail ----
    const int rb2 = bid - 512;       // 0..3
    const int e   = rb2 * 128 + (tid >> 1);  // entry (l*128+c), 0..511
    const int hh  = tid & 1;
    float s = 0.f;
    for (int b = hh * 128; b < hh * 128 + 128; ++b) s += Gpart[b * 512 + e];
    s += __shfl_xor(s, 1, 64);
    if (hh == 0) G[e] = s;
    if (rb2 == 0 && tid < 4) {
      int cth = 0;
      for (int b = 0; b < 256; ++b) cth += Hpart[b * 4 + tid];
      hist[tid] = cth;
    }
    return;
  }

  const int lane = tid & 63;
  const int wave = tid >> 6;
  const int m    = lane & 31;
  const int half = lane >> 5;
  const int rb   = bid >> 4;
  const int sp   = bid & 15;
  const int r0   = rb * 256 + wave * 64;
  const int col0 = sp * 512;

  // A fragments: 2 rowsets x 8 k-chunks (64 VGPR), resident all kernel
  bf16x8 afrag[2][8];
#pragma unroll
  for (int rs = 0; rs < 2; ++rs)
#pragma unroll
    for (int s = 0; s < 8; ++s)
      afrag[rs][s] = *(const bf16x8*)(Xb + (r0 + rs * 32 + m) * CDIM + half * 8 + s * 16);

  float accS0[16], accS1[16];
#pragma unroll
  for (int r = 0; r < 16; ++r) { accS0[r] = 0.f; accS1[r] = 0.f; }

  const unsigned short* bptr = Xb + (col0 + m) * CDIM + half * 8;
  bf16x8 bf[2][8];
#pragma unroll
  for (int s = 0; s < 8; ++s) bf[0][s] = *(const bf16x8*)(bptr + s * 16);

#pragma unroll 2
  for (int g = 0; g < 16; ++g) {
    const int p = g & 1;
    if (g < 15) {
      const unsigned short* np = bptr + (g + 1) * 32 * CDIM;
#pragma unroll
      for (int s = 0; s < 8; ++s) bf[p ^ 1][s] = *(const bf16x8*)(np + s * 16);
    }
    f32x16 a0, a1;
#pragma unroll
    for (int r = 0; r < 16; ++r) { a0[r] = 0.f; a1[r] = 0.f; }
#pragma unroll
    for (int s = 0; s < 8; ++s)
      a0 = __builtin_amdgcn_mfma_f32_32x32x16_bf16(afrag[0][s], bf[p][s], a0, 0, 0, 0);
#pragma unroll
    for (int s = 0; s < 8; ++s)
      a1 = __builtin_amdgcn_mfma_f32_32x32x16_bf16(afrag[1][s], bf[p][s], a1, 0, 0, 0);

    const int colbase = col0 + g * 32;
    // rowset 0
    if (r0 == colbase) {
      const int colg = colbase + m;
#pragma unroll
      for (int r = 0; r < 16; ++r) {
        int   row = r0 + (r & 3) + 8 * (r >> 2) + 4 * half;
        float arg = (row == colg) ? -1e30f : a0[r] * C1F;
        accS0[r] += fexp2(arg);
      }
    } else {
#pragma unroll
      for (int r = 0; r < 16; ++r) accS0[r] += fexp2(a0[r] * C1F);
    }
    // rowset 1
    if (r0 + 32 == colbase) {
      const int colg = colbase + m;
#pragma unroll
      for (int r = 0; r < 16; ++r) {
        int   row = r0 + 32 + (r & 3) + 8 * (r >> 2) + 4 * half;
        float arg = (row == colg) ? -1e30f : a1[r] * C1F;
        accS1[r] += fexp2(arg);
      }
    } else {
#pragma unroll
      for (int r = 0; r < 16; ++r) accS1[r] += fexp2(a1[r] * C1F);
    }
  }

  // reduce across the 32 columns (lanes) of each half, one atomic per row
#pragma unroll
  for (int r = 0; r < 16; ++r) {
    float v = accS0[r];
    v += __shfl_xor(v, 1, 64);  v += __shfl_xor(v, 2, 64);
    v += __shfl_xor(v, 4, 64);  v += __shfl_xor(v, 8, 64);
    v += __shfl_xor(v, 16, 64);
    accS0[r] = v;
    float w = accS1[r];
    w += __shfl_xor(w, 1, 64);  w += __shfl_xor(w, 2, 64);
    w += __shfl_xor(w, 4, 64);  w += __shfl_xor(w, 8, 64);
    w += __shfl_xor(w, 16, 64);
    accS1[r] = w;
  }
  if (m == 0) {
#pragma unroll
    for (int r = 0; r < 16; ++r) {
      int rr = (r & 3) + 8 * (r >> 2) + 4 * half;
      atomicAdd(&S[r0 + rr], accS0[r]);
      atomicAdd(&S[r0 + 32 + rr], accS1[r]);
    }
  }
}

// ---------------------------------------------------------------------------
// K3: per-row loss + reduction + ticketed final division.
// loss_i = log(S_i) - (dot(x_i,G_lab) - |x_i|^2) / (T * (hist[lab]-1))
// ---------------------------------------------------------------------------
__global__ __launch_bounds__(256) void k_loss(const unsigned short* __restrict__ Xb,
                                              const int* __restrict__ labels,
                                              char* __restrict__ ws,
                                              float* __restrict__ out) {
  const float* S       = (const float*)(ws + OFF_S);
  const float* G       = (const float*)(ws + OFF_G);
  const int*   hist    = (const int*)(ws + OFF_HIST);
  float*       sumLoss = (float*)(ws + OFF_SUM);
  int*         ticket  = (int*)(ws + OFF_TKT);

  const int i   = blockIdx.x * 256 + threadIdx.x;
  const int lab = labels[i];
  const float* gl = G + lab * 128;
  const unsigned short* x = Xb + i * CDIM;
  float dot = 0.f, nrm = 0.f;
#pragma unroll
  for (int cc = 0; cc < 16; ++cc) {
    int4 q = *(const int4*)(x + cc * 8);
    const unsigned int* qs = (const unsigned int*)&q;
#pragma unroll
    for (int j = 0; j < 4; ++j) {
      unsigned int u = qs[j];
      float lo = __uint_as_float(u << 16);
      float hi = __uint_as_float(u & 0xffff0000u);
      int   ci = cc * 8 + j * 2;
      dot += lo * gl[ci] + hi * gl[ci + 1];
      nrm += lo * lo + hi * hi;
    }
  }
  float Si   = S[i];
  float cnt  = (float)(hist[lab] - 1);
  float loss = logf(Si) - (dot - nrm) / (TEMP * cnt);
  float contrib = (lab != 0) ? loss : 0.f;
  for (int mm = 1; mm < 64; mm <<= 1) contrib += __shfl_xor(contrib, mm, 64);
  __shared__ float ws4[4];
  if ((threadIdx.x & 63) == 0) ws4[threadIdx.x >> 6] = contrib;
  __syncthreads();
  if (threadIdx.x == 0) {
    atomicAdd(sumLoss, ws4[0] + ws4[1] + ws4[2] + ws4[3]);
    __threadfence();
    int t = atomicAdd(ticket, 1);
    if (t == 31) {  // all 32 block-sums are ordered before this
      float total = atomicAdd(sumLoss, 0.0f);  // atomic read sees all adds
      out[0] = total / (float)(NROWS - hist[0]);
    }
  }
}

// ---------------------------------------------------------------------------
extern "C" void kernel_launch(void* const* d_in, const int* in_sizes, int n_in,
                              void* d_out, int out_size, void* d_ws, size_t ws_size,
                              hipStream_t stream) {
  const float* F      = (const float*)d_in[0];
  const int*   labels = (const int*)d_in[1];
  char* ws = (char*)d_ws;
  unsigned short* Xb = (unsigned short*)ws;

  hipLaunchKernelGGL(k_pack, dim3(256), dim3(256), 0, stream, F, labels, ws);
  hipLaunchKernelGGL(k_main, dim3(516), dim3(256), 0, stream, Xb, ws);
  hipLaunchKernelGGL(k_loss, dim3(32), dim3(256), 0, stream, Xb, labels, ws,
                     (float*)d_out);
}

// Round 5
// 103.507 us; speedup vs baseline: 1.2089x; 1.0955x over previous
//
#include <hip/hip_runtime.h>
#include <hip/hip_bf16.h>
#include <stdint.h>

typedef short bf16x8 __attribute__((ext_vector_type(8)));
typedef float f32x16 __attribute__((ext_vector_type(16)));

#define NROWS 8192
#define CDIM  128
#define TEMP  0.07f
// log2(e)/0.07
#define C1F   20.6099291555566248f

// ws layout (bytes from ws base). Xb: [0, 2MB)
#define OFF_S     2097152   // float[8192] = 32768 B   (zeroed by k_pack)
#define OFF_SUM   2129920   // float sumLoss           (zeroed by k_pack)
#define OFF_TKT   2129924   // int ticket              (zeroed by k_pack)
#define OFF_G     2129984   // float[4][128] = 2048 B  (single-writer, k_tri tail)
#define OFF_HIST  2132032   // int[4]
#define OFF_GPART 2132096   // float[256][4][128] = 524288 B (k_pack, plain stores)
#define OFF_HPART 2656384   // int[256][4] = 4096 B
#define ZWORDS    8194      // S + sumLoss + ticket contiguous zero region

#define NTB   64            // 8192 / 128 tile grid
#define NTRI  2080          // 64*65/2 triangular tiles
#define TAILB 4             // G/H reduction blocks (bid 0..3)

__device__ __forceinline__ float bf2f(unsigned short u) {
  union { unsigned int i; float f; } x; x.i = ((unsigned int)u) << 16; return x.f;
}
__device__ __forceinline__ unsigned short f2bf(float f) {
  union { float f; unsigned int i; } x; x.f = f;
  unsigned int r = x.i + 0x7fffu + ((x.i >> 16) & 1u);  // RNE
  return (unsigned short)(r >> 16);
}
__device__ __forceinline__ float fexp2(float x) {
#if __has_builtin(__builtin_amdgcn_exp2f)
  return __builtin_amdgcn_exp2f(x);
#else
  return exp2f(x);
#endif
}

// ---------------------------------------------------------------------------
// K1: pack F (fp32 [8][128][1024]) -> Xb bf16 [8192][128]; zero stats region;
// emit per-block label-group sums Gpart[b][4][128] + hist partials Hpart[b][4].
// ---------------------------------------------------------------------------
__global__ __launch_bounds__(256) void k_pack(const float* __restrict__ F,
                                              const int* __restrict__ labels,
                                              char* __restrict__ ws) {
  unsigned short* Xb    = (unsigned short*)ws;
  float*          zbase = (float*)(ws + OFF_S);
  float*          Gpart = (float*)(ws + OFF_GPART);
  int*            Hpart = (int*)(ws + OFF_HPART);

  __shared__ float lds[128 * 33];
  __shared__ float gp[2][4][128];
  __shared__ int   lab_lds[32];

  const int tid = threadIdx.x;
  const int bid = blockIdx.x;

  {  // replaces the hipMemsetAsync node
    int idx = bid * 256 + tid;
    if (idx < ZWORDS) zbase[idx] = 0.0f;
  }

  const int g   = bid >> 5;
  const int hw0 = (bid & 31) << 5;
  const int n0  = g * 1024 + hw0;  // first row of this 32-row tile
  if (tid < 32) lab_lds[tid] = labels[n0 + tid];

#pragma unroll
  for (int p = 0; p < 16; ++p) {
    int c  = p * 8 + (tid >> 5);
    int hw = hw0 + (tid & 31);
    lds[c * 33 + (tid & 31)] = F[(g * 128 + c) * 1024 + hw];
  }
  __syncthreads();

  const int c = tid & 127;
  const int h = tid >> 7;  // wave-uniform
  float a0 = 0.f, a1 = 0.f, a2 = 0.f, a3 = 0.f;
#pragma unroll
  for (int p = 0; p < 16; ++p) {
    int hwl = p * 2 + h;
    float vf = lds[c * 33 + hwl];
    unsigned short vb = f2bf(vf);
    Xb[(n0 + hwl) * 128 + c] = vb;
    float v  = bf2f(vb);
    int  lab = lab_lds[hwl];  // wave-uniform broadcast
    a0 += (lab == 0) ? v : 0.f;
    a1 += (lab == 1) ? v : 0.f;
    a2 += (lab == 2) ? v : 0.f;
    a3 += (lab == 3) ? v : 0.f;
  }
  gp[h][0][c] = a0; gp[h][1][c] = a1; gp[h][2][c] = a2; gp[h][3][c] = a3;
  __syncthreads();
  if (tid < 128) {
#pragma unroll
    for (int l = 0; l < 4; ++l)
      Gpart[bid * 512 + l * 128 + tid] = gp[0][l][tid] + gp[1][l][tid];
  }
  if (tid < 4) {
    int hh = 0;
#pragma unroll
    for (int r = 0; r < 32; ++r) hh += (lab_lds[r] == tid);
    Hpart[bid * 4 + tid] = hh;
  }
}

// ---------------------------------------------------------------------------
// K2: triangular Gram with fused exp-sum. Tiles (rb,cb), rb<=cb, 128x128.
// exp(d_ij)==exp(d_ji): off-diag tiles add row-sums to S[rows] AND col-sums
// to S[cols] (col-sum = register-local over the 16 C-regs + xor-32 shuffle).
// A-frags direct from global (one-time); B staged via R2's conflict-free LDS
// layout (int4 (kchunk c, col n) at c*33+n), double-buffered 32-col groups.
// Blocks 0..3 = Gpart/Hpart reduction tail. ~100 VGPR -> 4 waves/SIMD.
// ---------------------------------------------------------------------------
__global__ __launch_bounds__(256, 4) void k_tri(const unsigned short* __restrict__ Xb,
                                                char* __restrict__ ws) {
  float* S     = (float*)(ws + OFF_S);
  float* Gpart = (float*)(ws + OFF_GPART);
  int*   Hpart = (int*)(ws + OFF_HPART);
  float* G     = (float*)(ws + OFF_G);
  int*   hist  = (int*)(ws + OFF_HIST);

  const int bid = blockIdx.x;
  const int tid = threadIdx.x;

  if (bid < TAILB) {  // ---- Gpart/Hpart reduction tail ----
    const int e  = bid * 128 + (tid >> 1);  // entry (l*128+c), 0..511
    const int hh = tid & 1;
    float s = 0.f;
    for (int b = hh * 128; b < hh * 128 + 128; ++b) s += Gpart[b * 512 + e];
    s += __shfl_xor(s, 1, 64);
    if (hh == 0) G[e] = s;
    if (bid == 0 && tid < 4) {
      int cth = 0;
      for (int b = 0; b < 256; ++b) cth += Hpart[b * 4 + tid];
      hist[tid] = cth;
    }
    return;
  }

  // ---- decode triangular tile (rb, cb), rb <= cb ----
  const int b = bid - TAILB;  // 0..2079
  int rb = (int)((129.0f - sqrtf((float)(129 * 129 - 8 * b))) * 0.5f);
  if (rb < 0) rb = 0;
  if (rb > 63) rb = 63;
#define TRIBASE(r) ((r) * 64 - ((r) * ((r) - 1)) / 2)
  while (rb > 0 && TRIBASE(rb) > b) --rb;
  while (TRIBASE(rb + 1) <= b) ++rb;
  const int cb   = rb + (b - TRIBASE(rb));
  const bool diag = (rb == cb);

  __shared__ int4 ldsB[2][528];  // 16.5 KB

  const int lane = tid & 63;
  const int wave = tid >> 6;
  const int m    = lane & 31;
  const int half = lane >> 5;
  const int r0   = rb * 128 + wave * 32;
  const int c0   = cb * 128;

  // A fragments: wave's 32 rows, full K=128 (32 VGPR, one-time scattered load)
  bf16x8 afrag[8];
#pragma unroll
  for (int s = 0; s < 8; ++s)
    afrag[s] = *(const bf16x8*)(Xb + (r0 + m) * CDIM + (half + 2 * s) * 8);

  float accS[16];
#pragma unroll
  for (int r = 0; r < 16; ++r) accS[r] = 0.f;
  float colAcc[4];

  // B staging: 32 cols per group, 4 groups, double-buffered
  const int n_l = tid >> 3;   // col in group 0..31
  const int bq  = tid & 7;    // chunk-pair
  const unsigned short* src = Xb + (c0 + n_l) * CDIM + bq * 16;
  int4 v0 = *(const int4*)src;
  int4 v1 = *(const int4*)(src + 8);
  ldsB[0][(2 * bq) * 33 + n_l]     = v0;
  ldsB[0][(2 * bq + 1) * 33 + n_l] = v1;
  src += 32 * CDIM;
  v0 = *(const int4*)src;
  v1 = *(const int4*)(src + 8);

#pragma unroll
  for (int g = 0; g < 4; ++g) {
    __syncthreads();
    if (g < 3) {
      const int nb = (g + 1) & 1;
      ldsB[nb][(2 * bq) * 33 + n_l]     = v0;
      ldsB[nb][(2 * bq + 1) * 33 + n_l] = v1;
    }
    if (g < 2) {
      src += 32 * CDIM;
      v0 = *(const int4*)src;
      v1 = *(const int4*)(src + 8);
    }
    const int cur = g & 1;
    f32x16 acc;
#pragma unroll
    for (int r = 0; r < 16; ++r) acc[r] = 0.f;
#pragma unroll
    for (int s = 0; s < 8; ++s) {
      bf16x8 bfrag = *(const bf16x8*)&ldsB[cur][(half + 2 * s) * 33 + m];
      acc = __builtin_amdgcn_mfma_f32_32x32x16_bf16(afrag[s], bfrag, acc, 0, 0, 0);
    }
    const int colbase = c0 + g * 32;
    float csum = 0.f;
    if (r0 == colbase) {  // diagonal-crossing tile (only when rb==cb, g==wave)
#pragma unroll
      for (int r = 0; r < 16; ++r) {
        int   rr  = (r & 3) + 8 * (r >> 2) + 4 * half;
        float arg = (rr == m) ? -1e30f : acc[r] * C1F;
        float e   = fexp2(arg);
        accS[r] += e;
        csum    += e;
      }
    } else {
#pragma unroll
      for (int r = 0; r < 16; ++r) {
        float e = fexp2(acc[r] * C1F);
        accS[r] += e;
        csum    += e;
      }
    }
    colAcc[g] = csum;
  }

  // row sums: reduce across 32 cols (lanes) per half, one atomic per row
#pragma unroll
  for (int r = 0; r < 16; ++r) {
    float v = accS[r];
    v += __shfl_xor(v, 1, 64);  v += __shfl_xor(v, 2, 64);
    v += __shfl_xor(v, 4, 64);  v += __shfl_xor(v, 8, 64);
    v += __shfl_xor(v, 16, 64);
    accS[r] = v;
  }
  if (m == 0) {
#pragma unroll
    for (int r = 0; r < 16; ++r) {
      int rr = (r & 3) + 8 * (r >> 2) + 4 * half;
      atomicAdd(&S[r0 + rr], accS[r]);
    }
  }

  // col sums (transpose contribution) — off-diagonal tiles only
  if (!diag) {
#pragma unroll
    for (int g = 0; g < 4; ++g) {
      float v = colAcc[g];
      v += __shfl_xor(v, 32, 64);  // combine the two halves (row subsets)
      if (half == 0) atomicAdd(&S[c0 + g * 32 + m], v);
    }
  }
}

// ---------------------------------------------------------------------------
// K3: per-row loss + reduction + ticketed final division.
// loss_i = log(S_i) - (dot(x_i,G_lab) - |x_i|^2) / (T * (hist[lab]-1))
// ---------------------------------------------------------------------------
__global__ __launch_bounds__(256) void k_loss(const unsigned short* __restrict__ Xb,
                                              const int* __restrict__ labels,
                                              char* __restrict__ ws,
                                              float* __restrict__ out) {
  const float* S       = (const float*)(ws + OFF_S);
  const float* G       = (const float*)(ws + OFF_G);
  const int*   hist    = (const int*)(ws + OFF_HIST);
  float*       sumLoss = (float*)(ws + OFF_SUM);
  int*         ticket  = (int*)(ws + OFF_TKT);

  const int i   = blockIdx.x * 256 + threadIdx.x;
  const int lab = labels[i];
  const float* gl = G + lab * 128;
  const unsigned short* x = Xb + i * CDIM;
  float dot = 0.f, nrm = 0.f;
#pragma unroll
  for (int cc = 0; cc < 16; ++cc) {
    int4 q = *(const int4*)(x + cc * 8);
    const unsigned int* qs = (const unsigned int*)&q;
#pragma unroll
    for (int j = 0; j < 4; ++j) {
      unsigned int u = qs[j];
      float lo = __uint_as_float(u << 16);
      float hi = __uint_as_float(u & 0xffff0000u);
      int   ci = cc * 8 + j * 2;
      dot += lo * gl[ci] + hi * gl[ci + 1];
      nrm += lo * lo + hi * hi;
    }
  }
  float Si   = S[i];
  float cnt  = (float)(hist[lab] - 1);
  float loss = logf(Si) - (dot - nrm) / (TEMP * cnt);
  float contrib = (lab != 0) ? loss : 0.f;
  for (int mm = 1; mm < 64; mm <<= 1) contrib += __shfl_xor(contrib, mm, 64);
  __shared__ float ws4[4];
  if ((threadIdx.x & 63) == 0) ws4[threadIdx.x >> 6] = contrib;
  __syncthreads();
  if (threadIdx.x == 0) {
    atomicAdd(sumLoss, ws4[0] + ws4[1] + ws4[2] + ws4[3]);
    __threadfence();
    int t = atomicAdd(ticket, 1);
    if (t == 31) {  // all 32 block-sums are ordered before this
      float total = atomicAdd(sumLoss, 0.0f);  // atomic read sees all adds
      out[0] = total / (float)(NROWS - hist[0]);
    }
  }
}

// ---------------------------------------------------------------------------
extern "C" void kernel_launch(void* const* d_in, const int* in_sizes, int n_in,
                              void* d_out, int out_size, void* d_ws, size_t ws_size,
                              hipStream_t stream) {
  const float* F      = (const float*)d_in[0];
  const int*   labels = (const int*)d_in[1];
  char* ws = (char*)d_ws;
  unsigned short* Xb = (unsigned short*)ws;

  hipLaunchKernelGGL(k_pack, dim3(256), dim3(256), 0, stream, F, labels, ws);
  hipLaunchKernelGGL(k_tri, dim3(NTRI + TAILB), dim3(256), 0, stream, Xb, ws);
  hipLaunchKernelGGL(k_loss, dim3(32), dim3(256), 0, stream, Xb, labels, ws,
                     (float*)d_out);
}

// Round 6
// 101.234 us; speedup vs baseline: 1.2361x; 1.0225x over previous
//
#include <hip/hip_runtime.h>
#include <hip/hip_bf16.h>
#include <stdint.h>

typedef short bf16x8 __attribute__((ext_vector_type(8)));
typedef float f32x16 __attribute__((ext_vector_type(16)));

#define NROWS 8192
#define CDIM  128
#define TEMP  0.07f
// log2(e)/0.07
#define C1F   20.6099291555566248f

// ws layout (bytes from ws base). Xb: [0, 2MB)
#define OFF_S     2097152   // float[8192] = 32768 B   (zeroed by k_pack)
#define OFF_SUM   2129920   // float sumLoss           (zeroed by k_pack)
#define OFF_TKT   2129924   // int ticket              (zeroed by k_pack)
#define OFF_G     2129984   // float[4][128] = 2048 B  (single-writer, k_tri tail)
#define OFF_HIST  2132032   // int[4]
#define OFF_GPART 2132096   // float[256][4][128] = 524288 B (k_pack, plain stores)
#define OFF_HPART 2656384   // int[256][4] = 4096 B
#define ZWORDS    8194      // S + sumLoss + ticket contiguous zero region

#define NTB   64            // 8192 / 128 tile grid
#define NTRI  2080          // 64*65/2 triangular tiles
#define TAILB 4             // G/H reduction blocks (bid 0..3)

__device__ __forceinline__ float bf2f(unsigned short u) {
  union { unsigned int i; float f; } x; x.i = ((unsigned int)u) << 16; return x.f;
}
__device__ __forceinline__ unsigned short f2bf(float f) {
  union { float f; unsigned int i; } x; x.f = f;
  unsigned int r = x.i + 0x7fffu + ((x.i >> 16) & 1u);  // RNE
  return (unsigned short)(r >> 16);
}
__device__ __forceinline__ float fexp2(float x) {
#if __has_builtin(__builtin_amdgcn_exp2f)
  return __builtin_amdgcn_exp2f(x);
#else
  return exp2f(x);
#endif
}

// ---------------------------------------------------------------------------
// K1: pack F (fp32 [8][128][1024]) -> Xb bf16 [8192][128]; zero stats region;
// emit per-block label-group sums Gpart[b][4][128] + hist partials Hpart[b][4].
// ---------------------------------------------------------------------------
__global__ __launch_bounds__(256) void k_pack(const float* __restrict__ F,
                                              const int* __restrict__ labels,
                                              char* __restrict__ ws) {
  unsigned short* Xb    = (unsigned short*)ws;
  float*          zbase = (float*)(ws + OFF_S);
  float*          Gpart = (float*)(ws + OFF_GPART);
  int*            Hpart = (int*)(ws + OFF_HPART);

  __shared__ float lds[128 * 33];
  __shared__ float gp[2][4][128];
  __shared__ int   lab_lds[32];

  const int tid = threadIdx.x;
  const int bid = blockIdx.x;

  {  // replaces the hipMemsetAsync node
    int idx = bid * 256 + tid;
    if (idx < ZWORDS) zbase[idx] = 0.0f;
  }

  const int g   = bid >> 5;
  const int hw0 = (bid & 31) << 5;
  const int n0  = g * 1024 + hw0;  // first row of this 32-row tile
  if (tid < 32) lab_lds[tid] = labels[n0 + tid];

#pragma unroll
  for (int p = 0; p < 16; ++p) {
    int c  = p * 8 + (tid >> 5);
    int hw = hw0 + (tid & 31);
    lds[c * 33 + (tid & 31)] = F[(g * 128 + c) * 1024 + hw];
  }
  __syncthreads();

  const int c = tid & 127;
  const int h = tid >> 7;  // wave-uniform
  float a0 = 0.f, a1 = 0.f, a2 = 0.f, a3 = 0.f;
#pragma unroll
  for (int p = 0; p < 16; ++p) {
    int hwl = p * 2 + h;
    float vf = lds[c * 33 + hwl];
    unsigned short vb = f2bf(vf);
    Xb[(n0 + hwl) * 128 + c] = vb;
    float v  = bf2f(vb);
    int  lab = lab_lds[hwl];  // wave-uniform broadcast
    a0 += (lab == 0) ? v : 0.f;
    a1 += (lab == 1) ? v : 0.f;
    a2 += (lab == 2) ? v : 0.f;
    a3 += (lab == 3) ? v : 0.f;
  }
  gp[h][0][c] = a0; gp[h][1][c] = a1; gp[h][2][c] = a2; gp[h][3][c] = a3;
  __syncthreads();
  if (tid < 128) {
#pragma unroll
    for (int l = 0; l < 4; ++l)
      Gpart[bid * 512 + l * 128 + tid] = gp[0][l][tid] + gp[1][l][tid];
  }
  if (tid < 4) {
    int hh = 0;
#pragma unroll
    for (int r = 0; r < 32; ++r) hh += (lab_lds[r] == tid);
    Hpart[bid * 4 + tid] = hh;
  }
}

// ---------------------------------------------------------------------------
// K2: triangular Gram with fused exp-sum. Tiles (rb,cb), rb<=cb, 128x128.
// SINGLE-BARRIER structure: all 4 B col-groups staged into LDS up front, one
// __syncthreads (the only vmcnt(0) drain), then 32 MFMA + epilogue barrier-
// free (LDS->MFMA scheduled by compiler's fine-grained lgkmcnt).
// exp(d_ij)==exp(d_ji): off-diag tiles add row-sums to S[rows] AND col-sums
// to S[cols]. Blocks 0..3 = Gpart/Hpart reduction tail.
// ---------------------------------------------------------------------------
__global__ __launch_bounds__(256, 4) void k_tri(const unsigned short* __restrict__ Xb,
                                                char* __restrict__ ws) {
  float* S     = (float*)(ws + OFF_S);
  float* Gpart = (float*)(ws + OFF_GPART);
  int*   Hpart = (int*)(ws + OFF_HPART);
  float* G     = (float*)(ws + OFF_G);
  int*   hist  = (int*)(ws + OFF_HIST);

  const int bid = blockIdx.x;
  const int tid = threadIdx.x;

  if (bid < TAILB) {  // ---- Gpart/Hpart reduction tail ----
    const int e  = bid * 128 + (tid >> 1);  // entry (l*128+c), 0..511
    const int hh = tid & 1;
    float s = 0.f;
    for (int b = hh * 128; b < hh * 128 + 128; ++b) s += Gpart[b * 512 + e];
    s += __shfl_xor(s, 1, 64);
    if (hh == 0) G[e] = s;
    if (bid == 0 && tid < 4) {
      int cth = 0;
      for (int b = 0; b < 256; ++b) cth += Hpart[b * 4 + tid];
      hist[tid] = cth;
    }
    return;
  }

  // ---- decode triangular tile (rb, cb), rb <= cb ----
  const int b = bid - TAILB;  // 0..2079
  int rb = (int)((129.0f - sqrtf((float)(129 * 129 - 8 * b))) * 0.5f);
  if (rb < 0) rb = 0;
  if (rb > 63) rb = 63;
#define TRIBASE(r) ((r) * 64 - ((r) * ((r) - 1)) / 2)
  while (rb > 0 && TRIBASE(rb) > b) --rb;
  while (TRIBASE(rb + 1) <= b) ++rb;
  const int cb   = rb + (b - TRIBASE(rb));
  const bool diag = (rb == cb);

  __shared__ int4 LB[4 * 528];  // 33 KB, 4 col-groups, layout c*33+n per group

  const int lane = tid & 63;
  const int wave = tid >> 6;
  const int m    = lane & 31;
  const int half = lane >> 5;
  const int r0   = rb * 128 + wave * 32;
  const int c0   = cb * 128;

  // A fragments first (independent one-time global loads, in flight during
  // staging; covered by the single barrier drain)
  bf16x8 afrag[8];
#pragma unroll
  for (int s = 0; s < 8; ++s)
    afrag[s] = *(const bf16x8*)(Xb + (r0 + m) * CDIM + (half + 2 * s) * 8);

  // B staging: ALL 4 groups (128 cols x 128 k), coalesced 2KB/wave per group
  const int n_l = tid >> 3;   // col in group 0..31
  const int bq  = tid & 7;    // chunk-pair
  {
    const unsigned short* src = Xb + (c0 + n_l) * CDIM + bq * 16;
#pragma unroll
    for (int g = 0; g < 4; ++g) {
      int4 v0 = *(const int4*)(src + g * 32 * CDIM);
      int4 v1 = *(const int4*)(src + g * 32 * CDIM + 8);
      LB[g * 528 + (2 * bq) * 33 + n_l]     = v0;
      LB[g * 528 + (2 * bq + 1) * 33 + n_l] = v1;
    }
  }
  __syncthreads();  // the ONE barrier (and the one vmcnt(0) drain) per block

  float accS[16];
#pragma unroll
  for (int r = 0; r < 16; ++r) accS[r] = 0.f;
  float colAcc[4];

#pragma unroll
  for (int g = 0; g < 4; ++g) {
    f32x16 acc;
#pragma unroll
    for (int r = 0; r < 16; ++r) acc[r] = 0.f;
#pragma unroll
    for (int s = 0; s < 8; ++s) {
      bf16x8 bfrag = *(const bf16x8*)&LB[g * 528 + (half + 2 * s) * 33 + m];
      acc = __builtin_amdgcn_mfma_f32_32x32x16_bf16(afrag[s], bfrag, acc, 0, 0, 0);
    }
    const int colbase = c0 + g * 32;
    float csum = 0.f;
    if (r0 == colbase) {  // diagonal-crossing (only when rb==cb and g==wave)
#pragma unroll
      for (int r = 0; r < 16; ++r) {
        int   rr  = (r & 3) + 8 * (r >> 2) + 4 * half;
        float arg = (rr == m) ? -1e30f : acc[r] * C1F;
        float e   = fexp2(arg);
        accS[r] += e;
        csum    += e;
      }
    } else {
#pragma unroll
      for (int r = 0; r < 16; ++r) {
        float e = fexp2(acc[r] * C1F);
        accS[r] += e;
        csum    += e;
      }
    }
    colAcc[g] = csum;
  }

  // row sums: reduce across 32 cols (lanes) per half, one atomic per row
#pragma unroll
  for (int r = 0; r < 16; ++r) {
    float v = accS[r];
    v += __shfl_xor(v, 1, 64);  v += __shfl_xor(v, 2, 64);
    v += __shfl_xor(v, 4, 64);  v += __shfl_xor(v, 8, 64);
    v += __shfl_xor(v, 16, 64);
    accS[r] = v;
  }
  if (m == 0) {
#pragma unroll
    for (int r = 0; r < 16; ++r) {
      int rr = (r & 3) + 8 * (r >> 2) + 4 * half;
      atomicAdd(&S[r0 + rr], accS[r]);
    }
  }

  // col sums (transpose contribution) — off-diagonal tiles only
  if (!diag) {
#pragma unroll
    for (int g = 0; g < 4; ++g) {
      float v = colAcc[g];
      v += __shfl_xor(v, 32, 64);  // combine the two halves (row subsets)
      if (half == 0) atomicAdd(&S[c0 + g * 32 + m], v);
    }
  }
}

// ---------------------------------------------------------------------------
// K3: per-row loss + reduction + ticketed final division.
// loss_i = log(S_i) - (dot(x_i,G_lab) - |x_i|^2) / (T * (hist[lab]-1))
// ---------------------------------------------------------------------------
__global__ __launch_bounds__(256) void k_loss(const unsigned short* __restrict__ Xb,
                                              const int* __restrict__ labels,
                                              char* __restrict__ ws,
                                              float* __restrict__ out) {
  const float* S       = (const float*)(ws + OFF_S);
  const float* G       = (const float*)(ws + OFF_G);
  const int*   hist    = (const int*)(ws + OFF_HIST);
  float*       sumLoss = (float*)(ws + OFF_SUM);
  int*         ticket  = (int*)(ws + OFF_TKT);

  const int i   = blockIdx.x * 256 + threadIdx.x;
  const int lab = labels[i];
  const float* gl = G + lab * 128;
  const unsigned short* x = Xb + i * CDIM;
  float dot = 0.f, nrm = 0.f;
#pragma unroll
  for (int cc = 0; cc < 16; ++cc) {
    int4 q = *(const int4*)(x + cc * 8);
    const unsigned int* qs = (const unsigned int*)&q;
#pragma unroll
    for (int j = 0; j < 4; ++j) {
      unsigned int u = qs[j];
      float lo = __uint_as_float(u << 16);
      float hi = __uint_as_float(u & 0xffff0000u);
      int   ci = cc * 8 + j * 2;
      dot += lo * gl[ci] + hi * gl[ci + 1];
      nrm += lo * lo + hi * hi;
    }
  }
  float Si   = S[i];
  float cnt  = (float)(hist[lab] - 1);
  float loss = logf(Si) - (dot - nrm) / (TEMP * cnt);
  float contrib = (lab != 0) ? loss : 0.f;
  for (int mm = 1; mm < 64; mm <<= 1) contrib += __shfl_xor(contrib, mm, 64);
  __shared__ float ws4[4];
  if ((threadIdx.x & 63) == 0) ws4[threadIdx.x >> 6] = contrib;
  __syncthreads();
  if (threadIdx.x == 0) {
    atomicAdd(sumLoss, ws4[0] + ws4[1] + ws4[2] + ws4[3]);
    __threadfence();
    int t = atomicAdd(ticket, 1);
    if (t == 31) {  // all 32 block-sums are ordered before this
      float total = atomicAdd(sumLoss, 0.0f);  // atomic read sees all adds
      out[0] = total / (float)(NROWS - hist[0]);
    }
  }
}

// ---------------------------------------------------------------------------
extern "C" void kernel_launch(void* const* d_in, const int* in_sizes, int n_in,
                              void* d_out, int out_size, void* d_ws, size_t ws_size,
                              hipStream_t stream) {
  const float* F      = (const float*)d_in[0];
  const int*   labels = (const int*)d_in[1];
  char* ws = (char*)d_ws;
  unsigned short* Xb = (unsigned short*)ws;

  hipLaunchKernelGGL(k_pack, dim3(256), dim3(256), 0, stream, F, labels, ws);
  hipLaunchKernelGGL(k_tri, dim3(NTRI + TAILB), dim3(256), 0, stream, Xb, ws);
  hipLaunchKernelGGL(k_loss, dim3(32), dim3(256), 0, stream, Xb, labels, ws,
                     (float*)d_out);
}